// Round 6
// baseline (475.274 us; speedup 1.0000x reference)
//
#include <hip/hip_runtime.h>
#include <hip/hip_bf16.h>
#include <math.h>

#define B_ 4
#define L_ 4096
#define W_ 2560
#define H_ 10
#define NC_ 16        // chunks of 256 tokens (one chunk per k_gates block)
#define TRANGE 256    // tokens per k_gates block
#define AL_STRIDE 268 // shorts; rows 8B-aligned; 134 words = 6 mod 32 banks

typedef __attribute__((ext_vector_type(8))) short bf16x8;
typedef __attribute__((ext_vector_type(4))) float f32x4;

#define L2E 1.44269504088896f

__device__ inline float bf2f(unsigned short s){
  unsigned u = (unsigned)s << 16;
  return __builtin_bit_cast(float, u);
}
__device__ inline unsigned short f2bf(float f){
  unsigned u = __builtin_bit_cast(unsigned, f);
  u += 0x7fffu + ((u >> 16) & 1u);       // RNE
  return (unsigned short)(u >> 16);
}
__device__ inline float fast_rcp(float x){
#if __has_builtin(__builtin_amdgcn_rcpf)
  return __builtin_amdgcn_rcpf(x);
#else
  return 1.f / x;
#endif
}
__device__ inline float fast_sqrt(float x){
#if __has_builtin(__builtin_amdgcn_sqrtf)
  return __builtin_amdgcn_sqrtf(x);
#else
  return sqrtf(x);
#endif
}
__device__ inline float fast_sigmoid(float z){
  return fast_rcp(1.f + exp2f(-z * L2E));
}
__device__ inline unsigned pack_bf2(float lo, float hi){
  return ((unsigned)f2bf(hi) << 16) | (unsigned)f2bf(lo);
}

// ---------------------------------------------------------------------------
// k_prep: weights f32 -> bf16 in [h][n(512)][k(256)] layout; sp2 =
// -8*log2(e)*softplus(a_param).
// ---------------------------------------------------------------------------
__global__ __launch_bounds__(256) void k_prep(
    const float* __restrict__ w_x, const float* __restrict__ w_a,
    const float* __restrict__ a_param,
    unsigned short* __restrict__ Wt, float* __restrict__ sp_buf){
  int idx = blockIdx.x * 256 + threadIdx.x;
  if (idx < H_ * 512 * 256){
    int k = idx & 255;
    int n = (idx >> 8) & 511;
    int h = idx >> 17;
    float v = (n < 256) ? w_x[((size_t)h * 256 + k) * 256 + n]
                        : w_a[((size_t)h * 256 + k) * 256 + (n - 256)];
    Wt[idx] = f2bf(v);
  }
  if (idx < W_) sp_buf[idx] = -8.f * L2E * log1pf(expf(a_param[idx]));
}

// ---------------------------------------------------------------------------
// k_gates v4: block = (b, head, half, 256-token chunk), 512 thr, 8 waves.
// Wave owns 16 channels x 2 gates; B-frags (64 VGPR) pinned via asm clobber.
// 8 supersteps of 32 tokens: stage A (32x256 bf16) in LDS, 32 MFMAs/wave,
// fused epilogue computes per-token y_local (chunk-relative scan) + cumA
// (log2) via in-wave exclusive prefix; writes packed (lgA|y_local) bf16x2.
// Chunk totals (P,S) written once at block end.
// ---------------------------------------------------------------------------
__global__ __launch_bounds__(512, 3) void k_gates(
    const float* __restrict__ x, const int* __restrict__ segpos,
    const unsigned short* __restrict__ Wt,
    const float* __restrict__ b_x, const float* __restrict__ b_a,
    const float* __restrict__ sp_buf,
    unsigned* __restrict__ pk_buf,
    float* __restrict__ P_buf, float* __restrict__ S_buf){
  __shared__ alignas(16) unsigned short Al[32 * AL_STRIDE];

  const int bid   = blockIdx.x;
  const int range = bid & 15;          // chunk index
  const int half  = (bid >> 4) & 1;
  const int rest  = bid >> 5;
  const int h     = rest % H_;
  const int b     = rest / H_;
  const int t_base = range * TRANGE;

  const int tid  = threadIdx.x;
  const int wave = tid >> 6, lane = tid & 63;
  const int lr = lane & 15, hi = lane >> 4;
  const int c_loc = half * 128 + wave * 16 + lr;  // channel within head
  const int cg    = h * 256 + c_loc;              // global channel

  // ---- B fragments in registers: 8 k8 x 2 gates x 4 VGPR = 64 VGPR
  const unsigned short* Wh = Wt + (size_t)h * 512 * 256;
  bf16x8 bfx[8], bfa[8];
  #pragma unroll
  for (int k8 = 0; k8 < 8; k8++){
    bfx[k8] = *(const bf16x8*)(Wh + (size_t)c_loc * 256 + k8 * 32 + hi * 8);
    bfa[k8] = *(const bf16x8*)(Wh + (size_t)(c_loc + 256) * 256 + k8 * 32 + hi * 8);
  }
  const float bxv = b_x[h * 256 + c_loc];
  const float bav = b_a[h * 256 + c_loc];
  const float sp2 = sp_buf[cg];                   // -8*log2e*softplus
  // Pin the fragments: re-loading after this clobber would be unsound.
  asm volatile("" ::: "memory");

  const float* xh = x + ((size_t)b * L_ + t_base) * W_ + h * 256;
  const f32x4 zero = {0.f, 0.f, 0.f, 0.f};

  float Pch = 1.f, Sch = 0.f, Lch = 0.f;   // chunk scan state

  for (int ss = 0; ss < TRANGE / 32; ss++){
    __syncthreads();
    // stage A: 32 rows x 256 k, f32 -> bf16. 2048 float4-quads, 4/thread.
    #pragma unroll
    for (int rep = 0; rep < 4; rep++){
      int Q = tid + rep * 512;
      int row = Q >> 6, kq = Q & 63;
      float4 v = *(const float4*)(xh + (size_t)(ss * 32 + row) * W_ + kq * 4);
      uint2 st = { pack_bf2(v.x, v.y), pack_bf2(v.z, v.w) };
      *(uint2*)&Al[row * AL_STRIDE + kq * 4] = st;
    }
    __syncthreads();

    f32x4 accx[2] = {zero, zero}, acca[2] = {zero, zero};
    #pragma unroll
    for (int k8 = 0; k8 < 8; k8++){
      #pragma unroll
      for (int m = 0; m < 2; m++){
        union { bf16x8 v; uint2 u[2]; } af;
        const int off = (m * 16 + lr) * AL_STRIDE + k8 * 32 + hi * 8;
        af.u[0] = *(const uint2*)&Al[off];
        af.u[1] = *(const uint2*)&Al[off + 4];
        accx[m] = __builtin_amdgcn_mfma_f32_16x16x32_bf16(af.v, bfx[k8], accx[m], 0, 0, 0);
        acca[m] = __builtin_amdgcn_mfma_f32_16x16x32_bf16(af.v, bfa[k8], acca[m], 0, 0, 0);
      }
    }

    // ---- epilogue per m-tile (16 tokens), sequential in m
    #pragma unroll
    for (int m = 0; m < 2; m++){
      float av[4], nxv[4], la2v[4];
      float gp = 1.f, gs = 0.f, gl = 0.f;
      #pragma unroll
      for (int i = 0; i < 4; i++){
        const int trow = m * 16 + hi * 4 + i;
        const int t = t_base + ss * 32 + trow;
        const int seg = segpos[b * L_ + t];
        float gx = fast_sigmoid(accx[m][i] + bxv);
        float ga = fast_sigmoid(acca[m][i] + bav);
        float l2 = sp2 * ga;                       // log2(a)
        float a  = exp2f(l2);
        float mult = fast_sqrt(fmaf(-a, a, 1.f));  // sqrt(1-a^2)
        if (seg == 0){ a = 0.f; mult = 1.f; l2 = -INFINITY; }
        float xb = bf2f(Al[trow * AL_STRIDE + c_loc]);
        float nx = xb * gx * mult;
        av[i] = a; nxv[i] = nx; la2v[i] = l2;
        gs = fmaf(a, gs, nx); gp *= a; gl += l2;
      }
      // cross-hi exclusive prefix over 4 groups of 4 tokens
      float a1p = __shfl_xor(gp, 16), a1s = __shfl_xor(gs, 16), a1l = __shfl_xor(gl, 16);
      float pp = gp * a1p;
      float ps = (hi & 1) ? fmaf(a1s, gp, gs) : fmaf(gs, a1p, a1s);
      float pl = gl + a1l;
      float bp = __shfl_xor(pp, 32), bs = __shfl_xor(ps, 32), bl = __shfl_xor(pl, 32);
      float exP = (hi == 0) ? 1.f : (hi == 1) ? a1p : (hi == 2) ? bp : bp * a1p;
      float exS = (hi == 0) ? 0.f : (hi == 1) ? a1s : (hi == 2) ? bs : fmaf(bs, a1p, a1s);
      float exL = (hi == 0) ? 0.f : (hi == 1) ? a1l : (hi == 2) ? bl : bl + a1l;
      float cS = fmaf(Sch, exP, exS);   // h at end of previous group (chunk-rel)
      float cL = Lch + exL;             // lg cumA before this group
      // per-token outputs
      float pc = 1.f, sc = 0.f, lc = 0.f;
      #pragma unroll
      for (int i = 0; i < 4; i++){
        pc *= av[i]; sc = fmaf(av[i], sc, nxv[i]); lc += la2v[i];
        float yv = fmaf(pc, cS, sc);   // y_local (chunk-relative)
        float lg = lc + cL;            // log2 cumA (chunk-relative)
        const int t = t_base + ss * 32 + m * 16 + hi * 4 + i;
        pk_buf[((size_t)b * L_ + t) * W_ + cg] = pack_bf2(lg, yv);
      }
      // chunk-state update with m-tile totals
      float totP = pp * bp;
      float totS = (hi < 2) ? fmaf(ps, bp, bs) : fmaf(bs, pp, ps);
      float totL = pl + bl;
      Sch = fmaf(Sch, totP, totS);
      Pch = Pch * totP;
      Lch = Lch + totL;
    }
  }

  if (hi == 0){
    const size_t po = ((size_t)b * NC_ + range) * W_ + cg;
    P_buf[po] = Pch;
    S_buf[po] = Sch;
  }
}

// ---------------------------------------------------------------------------
// Phase B: carry scan across 16 chunks per (b, c); final carry == y[:, L-1]
// ---------------------------------------------------------------------------
__global__ __launch_bounds__(256) void k_scanB(
    const float* __restrict__ P_buf, const float* __restrict__ S_buf,
    float* __restrict__ carry_buf, float* __restrict__ y_last){
  const int g = blockIdx.x * 256 + threadIdx.x;   // 0 .. B*W-1
  const int b = g / W_, c = g % W_;
  float carry = 0.f;
  size_t off = (size_t)b * NC_ * W_ + c;
  #pragma unroll
  for (int ch = 0; ch < NC_; ch++){
    carry_buf[off] = carry;
    carry = fmaf(P_buf[off], carry, S_buf[off]);
    off += W_;
  }
  y_last[g] = carry;
}

// ---------------------------------------------------------------------------
// Phase C (elementwise): y = y_local + carry_chunk * 2^lgA, in place over pk.
// ---------------------------------------------------------------------------
__global__ __launch_bounds__(256) void k_scanC(
    unsigned* pky,                       // aliases y region: read pk, write f32
    const float* __restrict__ carry_buf){
  const unsigned total4 = B_ * L_ * (W_ / 4);
  const unsigned stride = gridDim.x * blockDim.x;
  for (unsigned g = blockIdx.x * blockDim.x + threadIdx.x; g < total4; g += stride){
    unsigned c4 = g % (W_ / 4);
    unsigned bt = g / (W_ / 4);
    unsigned t = bt & (L_ - 1);
    unsigned b = bt >> 12;
    uint4 pk = ((const uint4*)pky)[g];
    float4 cr = *(const float4*)&carry_buf[((size_t)b * NC_ + (t >> 8)) * W_ + c4 * 4];
    float4 yv;
    yv.x = fmaf(exp2f(__builtin_bit_cast(float, pk.x << 16)), cr.x,
                __builtin_bit_cast(float, pk.x & 0xFFFF0000u));
    yv.y = fmaf(exp2f(__builtin_bit_cast(float, pk.y << 16)), cr.y,
                __builtin_bit_cast(float, pk.y & 0xFFFF0000u));
    yv.z = fmaf(exp2f(__builtin_bit_cast(float, pk.z << 16)), cr.z,
                __builtin_bit_cast(float, pk.z & 0xFFFF0000u));
    yv.w = fmaf(exp2f(__builtin_bit_cast(float, pk.w << 16)), cr.w,
                __builtin_bit_cast(float, pk.w & 0xFFFF0000u));
    ((float4*)pky)[g] = yv;
  }
}

extern "C" void kernel_launch(void* const* d_in, const int* in_sizes, int n_in,
                              void* d_out, int out_size, void* d_ws, size_t ws_size,
                              hipStream_t stream){
  (void)in_sizes; (void)n_in; (void)out_size; (void)ws_size;
  const float* x       = (const float*)d_in[0];
  const int*   segpos  = (const int*)d_in[1];
  const float* a_param = (const float*)d_in[2];
  const float* w_x     = (const float*)d_in[3];
  const float* b_x     = (const float*)d_in[4];
  const float* w_a     = (const float*)d_in[5];
  const float* b_a     = (const float*)d_in[6];

  float* y      = (float*)d_out;                 // [B, L, W]; holds pk then y
  float* y_last = y + (size_t)B_ * L_ * W_;      // [B, W]
  unsigned* pk_buf = (unsigned*)d_out;

  char* p = (char*)d_ws;
  unsigned short* Wt = (unsigned short*)p;  p += (size_t)H_ * 512 * 256 * 2; // 2.6 MB
  float* sp_buf = (float*)p;                p += (size_t)W_ * 4;
  float* P_buf = (float*)p;                 p += (size_t)B_ * NC_ * W_ * 4;  // 655 KB
  float* S_buf = (float*)p;                 p += (size_t)B_ * NC_ * W_ * 4;
  float* carry_buf = (float*)p;             p += (size_t)B_ * NC_ * W_ * 4;

  k_prep<<<dim3((H_ * 512 * 256 + 255) / 256), dim3(256), 0, stream>>>(
      w_x, w_a, a_param, Wt, sp_buf);
  k_gates<<<dim3(B_ * H_ * 2 * NC_), dim3(512), 0, stream>>>(
      x, segpos, Wt, b_x, b_a, sp_buf, pk_buf, P_buf, S_buf);
  k_scanB<<<dim3((B_ * W_) / 256), dim3(256), 0, stream>>>(
      P_buf, S_buf, carry_buf, y_last);
  k_scanC<<<dim3(2048), dim3(256), 0, stream>>>(
      pk_buf, carry_buf);
}